// Round 1
// baseline (3295.517 us; speedup 1.0000x reference)
//
#include <hip/hip_runtime.h>

#define T_DIM 2048
#define B_DIM 50
#define F_DIM 750
#define H_DIM 100
#define G4    400            // 4*H
#define M_DIM (T_DIM * B_DIM) // 102400
#define OUT_N (T_DIM * 2)

__device__ __forceinline__ float fast_rcp(float x) { return __builtin_amdgcn_rcpf(x); }
__device__ __forceinline__ float sigm_f(float x) {
    return fast_rcp(1.0f + __expf(-x));
}
__device__ __forceinline__ float tanh_f(float x) {
    // 1 - 2/(e^{2x}+1); saturates correctly for |x| large (inf -> 1, 0 -> -1)
    return 1.0f - 2.0f * fast_rcp(__expf(2.0f * x) + 1.0f);
}

// ---------------------------------------------------------------------------
// Kernel 1: out init: out[t*2+o] = fc_b[o]
// ---------------------------------------------------------------------------
__global__ void init_out(const float* __restrict__ fcb, float* __restrict__ out) {
    int i = blockIdx.x * 256 + threadIdx.x;
    if (i < OUT_N) out[i] = fcb[i & 1];
}

// ---------------------------------------------------------------------------
// Kernel 2: x_proj GEMM (fp32, VALU): xp[m, g] = sum_k x[m,k]*Wih[g,k] + b_ih[g] + b_hh[g]
// Tile 64x64, BK=32, 256 threads, 4x4 micro-tile per thread.
// ---------------------------------------------------------------------------
__global__ __launch_bounds__(256) void xproj_gemm(
    const float* __restrict__ x,     // (M, 750)
    const float* __restrict__ Wih,   // (400, 750)
    const float* __restrict__ bih,
    const float* __restrict__ bhh,
    float* __restrict__ xp)          // (M, 400)
{
    const int m0 = blockIdx.x * 64;
    const int g0 = blockIdx.y * 64;
    __shared__ float As[32][68];     // k-major, stride 68 keeps 16B alignment
    __shared__ float Bs[32][68];

    const int tid  = threadIdx.x;
    const int tx   = tid & 15;       // n dir
    const int ty   = tid >> 4;       // m dir
    const int lrow = tid >> 3;       // 0..31
    const int lcol = (tid & 7) << 2; // 0,4,...,28

    float acc[4][4] = {};

    for (int k0 = 0; k0 < F_DIM; k0 += 32) {
        #pragma unroll
        for (int rr = 0; rr < 2; ++rr) {
            const int row = lrow + rr * 32;
            const int k = k0 + lcol;
            // ---- A tile (x) ----
            {
                const int m = m0 + row;
                float4 v = make_float4(0.f, 0.f, 0.f, 0.f);
                if (k + 4 <= F_DIM) {
                    v = *reinterpret_cast<const float4*>(&x[(size_t)m * F_DIM + k]);
                } else {
                    float tmp[4] = {0.f, 0.f, 0.f, 0.f};
                    #pragma unroll
                    for (int q = 0; q < 4; ++q)
                        if (k + q < F_DIM) tmp[q] = x[(size_t)m * F_DIM + k + q];
                    v = make_float4(tmp[0], tmp[1], tmp[2], tmp[3]);
                }
                As[lcol + 0][row] = v.x;
                As[lcol + 1][row] = v.y;
                As[lcol + 2][row] = v.z;
                As[lcol + 3][row] = v.w;
            }
            // ---- B tile (Wih) ----
            {
                const int g = g0 + row;
                float4 v = make_float4(0.f, 0.f, 0.f, 0.f);
                if (g < G4) {
                    if (k + 4 <= F_DIM) {
                        v = *reinterpret_cast<const float4*>(&Wih[(size_t)g * F_DIM + k]);
                    } else {
                        float tmp[4] = {0.f, 0.f, 0.f, 0.f};
                        #pragma unroll
                        for (int q = 0; q < 4; ++q)
                            if (k + q < F_DIM) tmp[q] = Wih[(size_t)g * F_DIM + k + q];
                        v = make_float4(tmp[0], tmp[1], tmp[2], tmp[3]);
                    }
                }
                Bs[lcol + 0][row] = v.x;
                Bs[lcol + 1][row] = v.y;
                Bs[lcol + 2][row] = v.z;
                Bs[lcol + 3][row] = v.w;
            }
        }
        __syncthreads();

        #pragma unroll
        for (int kk = 0; kk < 32; ++kk) {
            float4 a = *reinterpret_cast<const float4*>(&As[kk][ty * 4]);
            float4 b = *reinterpret_cast<const float4*>(&Bs[kk][tx * 4]);
            acc[0][0] = fmaf(a.x, b.x, acc[0][0]);
            acc[0][1] = fmaf(a.x, b.y, acc[0][1]);
            acc[0][2] = fmaf(a.x, b.z, acc[0][2]);
            acc[0][3] = fmaf(a.x, b.w, acc[0][3]);
            acc[1][0] = fmaf(a.y, b.x, acc[1][0]);
            acc[1][1] = fmaf(a.y, b.y, acc[1][1]);
            acc[1][2] = fmaf(a.y, b.z, acc[1][2]);
            acc[1][3] = fmaf(a.y, b.w, acc[1][3]);
            acc[2][0] = fmaf(a.z, b.x, acc[2][0]);
            acc[2][1] = fmaf(a.z, b.y, acc[2][1]);
            acc[2][2] = fmaf(a.z, b.z, acc[2][2]);
            acc[2][3] = fmaf(a.z, b.w, acc[2][3]);
            acc[3][0] = fmaf(a.w, b.x, acc[3][0]);
            acc[3][1] = fmaf(a.w, b.y, acc[3][1]);
            acc[3][2] = fmaf(a.w, b.z, acc[3][2]);
            acc[3][3] = fmaf(a.w, b.w, acc[3][3]);
        }
        __syncthreads();
    }

    // epilogue: add bias, store (float4 per row where valid)
    const int gbase = g0 + tx * 4;
    if (gbase + 3 < G4) {
        float bcol[4];
        #pragma unroll
        for (int j = 0; j < 4; ++j) bcol[j] = bih[gbase + j] + bhh[gbase + j];
        #pragma unroll
        for (int i = 0; i < 4; ++i) {
            const int m = m0 + ty * 4 + i;
            float4 o = make_float4(acc[i][0] + bcol[0], acc[i][1] + bcol[1],
                                   acc[i][2] + bcol[2], acc[i][3] + bcol[3]);
            *reinterpret_cast<float4*>(&xp[(size_t)m * G4 + gbase]) = o;
        }
    }
}

// ---------------------------------------------------------------------------
// Kernel 3: LSTM scan. One block per batch item, 512 threads.
//   threads 0..399: gate g (W_hh row in 100 VGPRs), threads 448..511: fused FC.
//   h lives in LDS (broadcast reads), c in regs of threads 0..99.
// ---------------------------------------------------------------------------
__global__ __launch_bounds__(512) void lstm_scan(
    const float* __restrict__ xp,    // (T, B, 400)
    const float* __restrict__ Whh,   // (400, 100)
    const float* __restrict__ fcW,   // (2, 5000)
    float* __restrict__ out)         // (T, 2), pre-initialized with fc_b
{
    const int b = blockIdx.x;
    const int tid = threadIdx.x;
    const int g = tid;

    __shared__ __align__(16) float h_lds[H_DIM];
    __shared__ float gates_lds[G4];

    float w[H_DIM];
    if (g < G4) {
        #pragma unroll
        for (int k4 = 0; k4 < 25; ++k4) {
            float4 v = *reinterpret_cast<const float4*>(&Whh[(size_t)g * H_DIM + k4 * 4]);
            w[k4 * 4 + 0] = v.x;
            w[k4 * 4 + 1] = v.y;
            w[k4 * 4 + 2] = v.z;
            w[k4 * 4 + 3] = v.w;
        }
    }
    float c = 0.f;
    if (tid < H_DIM) h_lds[tid] = 0.f;

    // FC weights for wave 7
    const int l = tid - 448;
    float fc0a = 0.f, fc0b = 0.f, fc1a = 0.f, fc1b = 0.f;
    if (tid >= 448) {
        fc0a = fcW[b * H_DIM + l];
        fc1a = fcW[5000 + b * H_DIM + l];
        if (l < 36) {
            fc0b = fcW[b * H_DIM + l + 64];
            fc1b = fcW[5000 + b * H_DIM + l + 64];
        }
    }
    __syncthreads();

    float xpv = (g < G4) ? xp[(size_t)b * G4 + g] : 0.f;

    for (int t = 0; t < T_DIM; ++t) {
        // prefetch next step's input projection (independent of state)
        float xp_next = (g < G4 && t + 1 < T_DIM)
                        ? xp[(size_t)((t + 1) * B_DIM + b) * G4 + g] : 0.f;

        // phase 1: gates = xp + W_hh . h
        if (g < G4) {
            float acc = xpv;
            #pragma unroll
            for (int k4 = 0; k4 < 25; ++k4) {
                float4 hv = *reinterpret_cast<const float4*>(&h_lds[k4 * 4]);
                acc = fmaf(w[k4 * 4 + 0], hv.x, acc);
                acc = fmaf(w[k4 * 4 + 1], hv.y, acc);
                acc = fmaf(w[k4 * 4 + 2], hv.z, acc);
                acc = fmaf(w[k4 * 4 + 3], hv.w, acc);
            }
            float act = (g >= 200 && g < 300) ? tanh_f(acc) : sigm_f(acc);
            gates_lds[g] = act;
        }
        __syncthreads();

        // phase 2: state update (threads 0..99)
        if (tid < H_DIM) {
            float i_ = gates_lds[tid];
            float f_ = gates_lds[tid + 100];
            float g_ = gates_lds[tid + 200];
            float o_ = gates_lds[tid + 300];
            c = fmaf(f_, c, i_ * g_);
            h_lds[tid] = o_ * tanh_f(c);
        }
        __syncthreads();

        // phase 3: fused FC on h_t (wave 7); h_lds stable until after next barrier
        if (tid >= 448) {
            float h1 = h_lds[l];
            float h2 = (l < 36) ? h_lds[l + 64] : 0.f;
            float p0 = fc0a * h1 + fc0b * h2;
            float p1 = fc1a * h1 + fc1b * h2;
            #pragma unroll
            for (int off = 32; off > 0; off >>= 1) {
                p0 += __shfl_xor(p0, off);
                p1 += __shfl_xor(p1, off);
            }
            if (l == 0) {
                atomicAdd(&out[2 * t],     p0);
                atomicAdd(&out[2 * t + 1], p1);
            }
        }
        xpv = xp_next;
    }
}

// ---------------------------------------------------------------------------
extern "C" void kernel_launch(void* const* d_in, const int* in_sizes, int n_in,
                              void* d_out, int out_size, void* d_ws, size_t ws_size,
                              hipStream_t stream) {
    const float* x   = (const float*)d_in[0];
    const float* Wih = (const float*)d_in[1];
    const float* Whh = (const float*)d_in[2];
    const float* bih = (const float*)d_in[3];
    const float* bhh = (const float*)d_in[4];
    const float* fcW = (const float*)d_in[5];
    const float* fcb = (const float*)d_in[6];
    float* out = (float*)d_out;
    float* xp  = (float*)d_ws;   // 102400 * 400 * 4 = 163,840,000 bytes

    init_out<<<(OUT_N + 255) / 256, 256, 0, stream>>>(fcb, out);

    dim3 grid(M_DIM / 64, (G4 + 63) / 64);   // 1600 x 7
    xproj_gemm<<<grid, 256, 0, stream>>>(x, Wih, bih, bhh, xp);

    lstm_scan<<<B_DIM, 512, 0, stream>>>(xp, Whh, fcW, out);
}

// Round 2
// 2766.269 us; speedup vs baseline: 1.1913x; 1.1913x over previous
//
#include <hip/hip_runtime.h>

#define T_DIM 2048
#define B_DIM 50
#define F_DIM 750
#define H_DIM 100
#define G4    400             // 4*H
#define M_DIM (T_DIM * B_DIM) // 102400
#define OUT_N (T_DIM * 2)

__device__ __forceinline__ float fast_rcp(float x) { return __builtin_amdgcn_rcpf(x); }
__device__ __forceinline__ float tanh_f(float x) {
    return 1.0f - 2.0f * fast_rcp(__expf(2.0f * x) + 1.0f);
}

template <int PAT>
__device__ __forceinline__ float quad_bcast(float v) {
    return __int_as_float(__builtin_amdgcn_ds_swizzle(__float_as_int(v), PAT));
}

// ---------------------------------------------------------------------------
// Kernel 1: x_proj GEMM (fp32, VALU): xp[m,g] = x[m,:].Wih[g,:] + b_ih[g]+b_hh[g]
// ---------------------------------------------------------------------------
__global__ __launch_bounds__(256) void xproj_gemm(
    const float* __restrict__ x,     // (M, 750)
    const float* __restrict__ Wih,   // (400, 750)
    const float* __restrict__ bih,
    const float* __restrict__ bhh,
    float* __restrict__ xp)          // (M, 400)
{
    const int m0 = blockIdx.x * 64;
    const int g0 = blockIdx.y * 64;
    __shared__ float As[32][68];
    __shared__ float Bs[32][68];

    const int tid  = threadIdx.x;
    const int tx   = tid & 15;
    const int ty   = tid >> 4;
    const int lrow = tid >> 3;
    const int lcol = (tid & 7) << 2;

    float acc[4][4] = {};

    for (int k0 = 0; k0 < F_DIM; k0 += 32) {
        #pragma unroll
        for (int rr = 0; rr < 2; ++rr) {
            const int row = lrow + rr * 32;
            const int k = k0 + lcol;
            {
                const int m = m0 + row;
                float4 v = make_float4(0.f, 0.f, 0.f, 0.f);
                if (k + 4 <= F_DIM) {
                    v = *reinterpret_cast<const float4*>(&x[(size_t)m * F_DIM + k]);
                } else {
                    float tmp[4] = {0.f, 0.f, 0.f, 0.f};
                    #pragma unroll
                    for (int q = 0; q < 4; ++q)
                        if (k + q < F_DIM) tmp[q] = x[(size_t)m * F_DIM + k + q];
                    v = make_float4(tmp[0], tmp[1], tmp[2], tmp[3]);
                }
                As[lcol + 0][row] = v.x;
                As[lcol + 1][row] = v.y;
                As[lcol + 2][row] = v.z;
                As[lcol + 3][row] = v.w;
            }
            {
                const int g = g0 + row;
                float4 v = make_float4(0.f, 0.f, 0.f, 0.f);
                if (g < G4) {
                    if (k + 4 <= F_DIM) {
                        v = *reinterpret_cast<const float4*>(&Wih[(size_t)g * F_DIM + k]);
                    } else {
                        float tmp[4] = {0.f, 0.f, 0.f, 0.f};
                        #pragma unroll
                        for (int q = 0; q < 4; ++q)
                            if (k + q < F_DIM) tmp[q] = Wih[(size_t)g * F_DIM + k + q];
                        v = make_float4(tmp[0], tmp[1], tmp[2], tmp[3]);
                    }
                }
                Bs[lcol + 0][row] = v.x;
                Bs[lcol + 1][row] = v.y;
                Bs[lcol + 2][row] = v.z;
                Bs[lcol + 3][row] = v.w;
            }
        }
        __syncthreads();

        #pragma unroll
        for (int kk = 0; kk < 32; ++kk) {
            float4 a = *reinterpret_cast<const float4*>(&As[kk][ty * 4]);
            float4 b = *reinterpret_cast<const float4*>(&Bs[kk][tx * 4]);
            acc[0][0] = fmaf(a.x, b.x, acc[0][0]);
            acc[0][1] = fmaf(a.x, b.y, acc[0][1]);
            acc[0][2] = fmaf(a.x, b.z, acc[0][2]);
            acc[0][3] = fmaf(a.x, b.w, acc[0][3]);
            acc[1][0] = fmaf(a.y, b.x, acc[1][0]);
            acc[1][1] = fmaf(a.y, b.y, acc[1][1]);
            acc[1][2] = fmaf(a.y, b.z, acc[1][2]);
            acc[1][3] = fmaf(a.y, b.w, acc[1][3]);
            acc[2][0] = fmaf(a.z, b.x, acc[2][0]);
            acc[2][1] = fmaf(a.z, b.y, acc[2][1]);
            acc[2][2] = fmaf(a.z, b.z, acc[2][2]);
            acc[2][3] = fmaf(a.z, b.w, acc[2][3]);
            acc[3][0] = fmaf(a.w, b.x, acc[3][0]);
            acc[3][1] = fmaf(a.w, b.y, acc[3][1]);
            acc[3][2] = fmaf(a.w, b.z, acc[3][2]);
            acc[3][3] = fmaf(a.w, b.w, acc[3][3]);
        }
        __syncthreads();
    }

    const int gbase = g0 + tx * 4;
    if (gbase + 3 < G4) {
        float bcol[4];
        #pragma unroll
        for (int j = 0; j < 4; ++j) bcol[j] = bih[gbase + j] + bhh[gbase + j];
        #pragma unroll
        for (int i = 0; i < 4; ++i) {
            const int m = m0 + ty * 4 + i;
            float4 o = make_float4(acc[i][0] + bcol[0], acc[i][1] + bcol[1],
                                   acc[i][2] + bcol[2], acc[i][3] + bcol[3]);
            *reinterpret_cast<float4*>(&xp[(size_t)m * G4 + gbase]) = o;
        }
    }
}

// ---------------------------------------------------------------------------
// Kernel 2: LSTM scan, quad-local cell.
//   448 threads; thread = gate q (tid&3) of hidden unit j (tid>>2).
//   W_hh row in 100 VGPRs. h double-buffered in LDS -> ONE barrier per step.
//   State update via ds_swizzle quad broadcasts (no LDS round-trip).
//   h_t stored into head of consumed xp row (t,b) -> FC reads it later.
// ---------------------------------------------------------------------------
__global__ __launch_bounds__(448) void lstm_scan(
    float* __restrict__ xp,          // (T*B, 400); rows also receive h
    const float* __restrict__ Whh)   // (400, 100)
{
    const int b   = blockIdx.x;
    const int tid = threadIdx.x;
    const int q   = tid & 3;         // 0=i 1=f 2=g 3=o
    const int j   = tid >> 2;        // hidden unit 0..111
    const bool active = (j < H_DIM);
    const int row = active ? (q * H_DIM + j) : 0;   // W_hh / xp gate row

    __shared__ __align__(16) float hbuf[2][H_DIM];

    float w[H_DIM];
    #pragma unroll
    for (int k4 = 0; k4 < 25; ++k4) {
        float4 v = *reinterpret_cast<const float4*>(&Whh[(size_t)row * H_DIM + k4 * 4]);
        w[k4 * 4 + 0] = v.x;
        w[k4 * 4 + 1] = v.y;
        w[k4 * 4 + 2] = v.z;
        w[k4 * 4 + 3] = v.w;
    }
    if (tid < H_DIM) { hbuf[0][tid] = 0.f; hbuf[1][tid] = 0.f; }

    float c = 0.f;
    const float s_act = (q == 2) ? 2.0f : 1.0f;   // tanh = 2*sigm(2x)-1
    __syncthreads();

    float xpv = xp[(size_t)b * G4 + row];          // step 0 input projection
    __syncthreads();   // all initial xp reads done before step-0 h stores

    int p = 0;
    for (int t = 0; t < T_DIM; ++t) {
        // prefetch next step's input projection (region t+1, untouched)
        float xp_next = (t + 1 < T_DIM)
            ? xp[(size_t)((t + 1) * B_DIM + b) * G4 + row] : 0.f;

        // gates = xp + W_hh . h   (4 partial accumulators for ILP)
        float a0 = xpv, a1 = 0.f, a2 = 0.f, a3 = 0.f;
        #pragma unroll
        for (int k4 = 0; k4 < 25; ++k4) {
            float4 hv = *reinterpret_cast<const float4*>(&hbuf[p][k4 * 4]);
            a0 = fmaf(w[k4 * 4 + 0], hv.x, a0);
            a1 = fmaf(w[k4 * 4 + 1], hv.y, a1);
            a2 = fmaf(w[k4 * 4 + 2], hv.z, a2);
            a3 = fmaf(w[k4 * 4 + 3], hv.w, a3);
        }
        float pre = (a0 + a1) + (a2 + a3);

        // unified activation: s*sigm(s*x) - (s-1)  (s=1 sigmoid, s=2 tanh)
        float act = s_act * fast_rcp(1.0f + __expf(-s_act * pre)) - (s_act - 1.0f);

        // quad exchange: all 4 lanes get i,f,g,o
        float i_ = quad_bcast<0x8000>(act);
        float f_ = quad_bcast<0x8055>(act);
        float g_ = quad_bcast<0x80AA>(act);
        float o_ = quad_bcast<0x80FF>(act);

        c = fmaf(f_, c, i_ * g_);
        float h = o_ * tanh_f(c);

        if (active && q == 0) {
            hbuf[p ^ 1][j] = h;
            // store h into consumed head of xp row (t,b): cols 0..99
            xp[(size_t)(t * B_DIM + b) * G4 + j] = h;
        }
        __syncthreads();
        p ^= 1;
        xpv = xp_next;
    }
}

// ---------------------------------------------------------------------------
// Kernel 3: FC. out[t,o] = fc_b[o] + sum_{b,j} h[t,b,j] * fcW[o, b*100+j]
//   h[t,b,j] lives at xp[(t*50+b)*400 + j].
// ---------------------------------------------------------------------------
__global__ __launch_bounds__(256) void fc_kernel(
    const float* __restrict__ hs,    // xp base
    const float* __restrict__ fcW,   // (2, 5000)
    const float* __restrict__ fcb,
    float* __restrict__ out)         // (T, 2)
{
    const int t   = blockIdx.x;
    const int tid = threadIdx.x;

    float p0 = 0.f, p1 = 0.f;
    for (int k = tid * 4; k < 5000; k += 1024) {
        const int bb = k / 100;
        const int jj = k - bb * 100;          // multiple of 4, <= 96
        const float4 hv = *reinterpret_cast<const float4*>(
            &hs[((size_t)t * B_DIM + bb) * G4 + jj]);
        const float4 w0 = *reinterpret_cast<const float4*>(&fcW[k]);
        const float4 w1 = *reinterpret_cast<const float4*>(&fcW[5000 + k]);
        p0 += hv.x * w0.x + hv.y * w0.y + hv.z * w0.z + hv.w * w0.w;
        p1 += hv.x * w1.x + hv.y * w1.y + hv.z * w1.z + hv.w * w1.w;
    }
    #pragma unroll
    for (int off = 32; off > 0; off >>= 1) {
        p0 += __shfl_xor(p0, off);
        p1 += __shfl_xor(p1, off);
    }
    __shared__ float red[8];
    const int wv = tid >> 6;
    if ((tid & 63) == 0) { red[wv * 2] = p0; red[wv * 2 + 1] = p1; }
    __syncthreads();
    if (tid == 0) {
        out[2 * t]     = fcb[0] + red[0] + red[2] + red[4] + red[6];
        out[2 * t + 1] = fcb[1] + red[1] + red[3] + red[5] + red[7];
    }
}

// ---------------------------------------------------------------------------
extern "C" void kernel_launch(void* const* d_in, const int* in_sizes, int n_in,
                              void* d_out, int out_size, void* d_ws, size_t ws_size,
                              hipStream_t stream) {
    const float* x   = (const float*)d_in[0];
    const float* Wih = (const float*)d_in[1];
    const float* Whh = (const float*)d_in[2];
    const float* bih = (const float*)d_in[3];
    const float* bhh = (const float*)d_in[4];
    const float* fcW = (const float*)d_in[5];
    const float* fcb = (const float*)d_in[6];
    float* out = (float*)d_out;
    float* xp  = (float*)d_ws;   // 102400 * 400 * 4 = 163,840,000 bytes

    dim3 grid(M_DIM / 64, (G4 + 63) / 64);   // 1600 x 7
    xproj_gemm<<<grid, 256, 0, stream>>>(x, Wih, bih, bhh, xp);

    lstm_scan<<<B_DIM, 448, 0, stream>>>(xp, Whh);

    fc_kernel<<<T_DIM, 256, 0, stream>>>(xp, fcW, fcb, out);
}

// Round 3
// 1704.028 us; speedup vs baseline: 1.9340x; 1.6234x over previous
//
#include <hip/hip_runtime.h>

#define T_DIM 2048
#define B_DIM 50
#define F_DIM 750
#define H_DIM 100
#define G4    400             // 4*H
#define M_DIM (T_DIM * B_DIM) // 102400
#define KPAD  768             // F padded to MFMA-friendly K

typedef __attribute__((ext_vector_type(8))) short short8v;  // 8 bf16
typedef __attribute__((ext_vector_type(4))) float f32x4;

__device__ __forceinline__ float fast_rcp(float x) { return __builtin_amdgcn_rcpf(x); }
__device__ __forceinline__ float sigm_f(float x) {
    return fast_rcp(1.0f + __expf(-x));
}
__device__ __forceinline__ float tanh_f(float x) {
    return 1.0f - 2.0f * fast_rcp(__expf(2.0f * x) + 1.0f);
}

__device__ __forceinline__ unsigned short f2bf(float f) {
    unsigned int u = __float_as_uint(f);
    u = (u + 0x7FFFu + ((u >> 16) & 1u)) >> 16;   // RNE
    return (unsigned short)u;
}
__device__ __forceinline__ float bf2f(unsigned short h) {
    return __uint_as_float(((unsigned int)h) << 16);
}

template <int CTRL>
__device__ __forceinline__ float qperm(float x) {
    return __int_as_float(__builtin_amdgcn_mov_dpp(__float_as_int(x), CTRL, 0xF, 0xF, false));
}

// ---------------------------------------------------------------------------
// Kernel 0: convert W_ih (400x750 fp32) -> W_hi/W_lo (400x768 bf16, k-padded 0)
// ---------------------------------------------------------------------------
__global__ __launch_bounds__(256) void wconv(
    const float* __restrict__ W,
    unsigned short* __restrict__ Whi,
    unsigned short* __restrict__ Wlo)
{
    int i = blockIdx.x * 256 + threadIdx.x;
    if (i >= G4 * KPAD) return;
    int g = i / KPAD, k = i - g * KPAD;
    float v = (k < F_DIM) ? W[g * F_DIM + k] : 0.f;
    unsigned short h = f2bf(v);
    Whi[i] = h;
    Wlo[i] = f2bf(v - bf2f(h));
}

// ---------------------------------------------------------------------------
// Kernel 1: xp = x @ W_ih^T + b_ih + b_hh via bf16 split MFMA.
//   Block: 256 thr (4 waves), M-tile 64, full N=400 (25 col-tiles: wave w gets
//   tiles w, w+4, ...). K: 24 steps of 32; x staged fp32->hi/lo bf16 in LDS
//   (double-buffered). 3 MFMAs per tile pair: hi*hi + hi*lo + lo*hi.
// ---------------------------------------------------------------------------
__global__ __launch_bounds__(256) void xproj_mfma(
    const float* __restrict__ x,            // (M, 750)
    const unsigned short* __restrict__ Whi, // (400, 768) bf16
    const unsigned short* __restrict__ Wlo,
    const float* __restrict__ bih,
    const float* __restrict__ bhh,
    float* __restrict__ xp)                 // (M, 400)
{
    const int m0   = blockIdx.x * 64;
    const int tid  = threadIdx.x;
    const int lane = tid & 63;
    const int w    = tid >> 6;            // wave 0..3
    const int fr   = lane & 15;           // frag row/col within 16
    const int fk   = (lane >> 4) * 8;     // frag k-offset (8 contiguous)

    __shared__ unsigned short Ahi[2][64][40];   // 32 k + 8 pad, 80B row stride
    __shared__ unsigned short Alo[2][64][40];

    f32x4 acc[4][7];
    #pragma unroll
    for (int s = 0; s < 4; ++s)
        #pragma unroll
        for (int t = 0; t < 7; ++t)
            acc[s][t] = (f32x4){0.f, 0.f, 0.f, 0.f};

    // per-tile bias (for this lane's column)
    float bias_t[7];
    #pragma unroll
    for (int tt = 0; tt < 7; ++tt) {
        const int nt = w + 4 * tt;
        if (nt < 25) {
            const int n = nt * 16 + fr;
            bias_t[tt] = bih[n] + bhh[n];
        } else bias_t[tt] = 0.f;
    }

    // staging: thread t loads 8 consecutive fp32 of x, splits to bf16 hi/lo
    const int sr  = tid >> 2;         // row 0..63
    const int sc  = (tid & 3) * 8;    // k-chunk 0/8/16/24
    #define STAGE(KS, NB)                                                        \
    {                                                                            \
        const int kg = (KS) * 32 + sc;                                           \
        const size_t base = (size_t)(m0 + sr) * F_DIM + kg;                      \
        float f[8];                                                              \
        _Pragma("unroll")                                                        \
        for (int i = 0; i < 8; i += 2) {                                         \
            if (kg + i + 1 < F_DIM) {                                            \
                float2 v = *reinterpret_cast<const float2*>(&x[base + i]);       \
                f[i] = v.x; f[i + 1] = v.y;                                      \
            } else {                                                             \
                f[i]     = (kg + i < F_DIM) ? x[base + i] : 0.f;                 \
                f[i + 1] = 0.f;                                                  \
            }                                                                    \
        }                                                                        \
        short8v vh, vl;                                                          \
        _Pragma("unroll")                                                        \
        for (int i = 0; i < 8; ++i) {                                            \
            unsigned short h = f2bf(f[i]);                                       \
            vh[i] = (short)h;                                                    \
            vl[i] = (short)f2bf(f[i] - bf2f(h));                                 \
        }                                                                        \
        *reinterpret_cast<short8v*>(&Ahi[NB][sr][sc]) = vh;                      \
        *reinterpret_cast<short8v*>(&Alo[NB][sr][sc]) = vl;                      \
    }

    STAGE(0, 0);
    asm volatile("s_waitcnt lgkmcnt(0)\ns_barrier" ::: "memory");

    for (int s = 0; s < 24; ++s) {
        const int cur = s & 1;
        // A fragments (hi/lo for 4 row-subtiles)
        short8v ah[4], al[4];
        #pragma unroll
        for (int st = 0; st < 4; ++st) {
            ah[st] = *reinterpret_cast<const short8v*>(&Ahi[cur][st * 16 + fr][fk]);
            al[st] = *reinterpret_cast<const short8v*>(&Alo[cur][st * 16 + fr][fk]);
        }
        if (s + 1 < 24) STAGE(s + 1, cur ^ 1);

        const int kb = s * 32 + fk;
        #pragma unroll
        for (int tt = 0; tt < 7; ++tt) {
            const int nt = w + 4 * tt;
            if (nt < 25) {
                const int n = nt * 16 + fr;
                const short8v bh = *reinterpret_cast<const short8v*>(&Whi[n * KPAD + kb]);
                const short8v bl = *reinterpret_cast<const short8v*>(&Wlo[n * KPAD + kb]);
                #pragma unroll
                for (int st = 0; st < 4; ++st) {
                    acc[st][tt] = __builtin_amdgcn_mfma_f32_16x16x32_bf16(ah[st], bh, acc[st][tt], 0, 0, 0);
                    acc[st][tt] = __builtin_amdgcn_mfma_f32_16x16x32_bf16(ah[st], bl, acc[st][tt], 0, 0, 0);
                    acc[st][tt] = __builtin_amdgcn_mfma_f32_16x16x32_bf16(al[st], bh, acc[st][tt], 0, 0, 0);
                }
            }
        }
        asm volatile("s_waitcnt lgkmcnt(0)\ns_barrier" ::: "memory");
    }

    // epilogue: C/D layout col = lane&15, row = (lane>>4)*4 + reg  [m89-verified]
    #pragma unroll
    for (int tt = 0; tt < 7; ++tt) {
        const int nt = w + 4 * tt;
        if (nt < 25) {
            const int n = nt * 16 + fr;
            #pragma unroll
            for (int st = 0; st < 4; ++st) {
                #pragma unroll
                for (int r = 0; r < 4; ++r) {
                    const int m = m0 + st * 16 + (lane >> 4) * 4 + r;
                    xp[(size_t)m * G4 + n] = acc[st][tt][r] + bias_t[tt];
                }
            }
        }
    }
    #undef STAGE
}

// ---------------------------------------------------------------------------
// Kernel 2: LSTM scan, quarter-split quad cell.
//   Lane q of quad j: k-quarter [25q,25q+25) of ALL 4 gates of unit j.
//   DPP quad butterfly sums partials -> every lane has all 4 pre-activations.
//   h -> hs (separate array) so xp stays read-only => lgkm-only barrier.
// ---------------------------------------------------------------------------
__global__ __launch_bounds__(448) void lstm_scan(
    const float* __restrict__ xp,    // (T*B, 400)
    const float* __restrict__ Whh,   // (400, 100)
    float* __restrict__ hs)          // (T*B, 100)
{
    const int b   = blockIdx.x;
    const int tid = threadIdx.x;
    const int q   = tid & 3;         // k-quarter
    const int j   = tid >> 2;        // hidden unit 0..111
    const int jc  = (j < H_DIM) ? j : (H_DIM - 1);
    const int row = q * H_DIM + jc;  // xp column for gate q of unit j

    __shared__ __align__(16) float hbuf[2][112];   // quarters at 28-float offsets

    // w[g][r]: Whh[g*100+jc][25q + r], r<25; pad 25..27 = 0
    float w[4][28];
    #pragma unroll
    for (int g = 0; g < 4; ++g) {
        const size_t base = (size_t)(g * H_DIM + jc) * H_DIM + 25 * q;
        #pragma unroll
        for (int r = 0; r < 25; ++r) w[g][r] = Whh[base + r];
        w[g][25] = w[g][26] = w[g][27] = 0.f;
    }
    if (tid < 112) { hbuf[0][tid] = 0.f; hbuf[1][tid] = 0.f; }

    const int hq = jc / 25, hr = jc - (jc / 25) * 25;
    const int hpos = hq * 28 + hr;

    float c = 0.f;
    float xpv = xp[(size_t)b * G4 + row];   // step-0 projection
    __syncthreads();

    int p = 0;
    for (int t = 0; t < T_DIM; ++t) {
        float xp_next = (t + 1 < T_DIM)
            ? xp[(size_t)((t + 1) * B_DIM + b) * G4 + row] : 0.f;

        // partial dots over this lane's quarter, all 4 gates
        float ac[4];
        ac[0] = (q == 0) ? xpv : 0.f;
        ac[1] = (q == 1) ? xpv : 0.f;
        ac[2] = (q == 2) ? xpv : 0.f;
        ac[3] = (q == 3) ? xpv : 0.f;
        #pragma unroll
        for (int k4 = 0; k4 < 7; ++k4) {
            float4 hv = *reinterpret_cast<const float4*>(&hbuf[p][28 * q + 4 * k4]);
            #pragma unroll
            for (int g = 0; g < 4; ++g) {
                ac[g] = fmaf(w[g][4 * k4 + 0], hv.x, ac[g]);
                ac[g] = fmaf(w[g][4 * k4 + 1], hv.y, ac[g]);
                ac[g] = fmaf(w[g][4 * k4 + 2], hv.z, ac[g]);
                ac[g] = fmaf(w[g][4 * k4 + 3], hv.w, ac[g]);
            }
        }
        // quad butterfly (VALU DPP, not LDS): every lane gets full sums
        #pragma unroll
        for (int g = 0; g < 4; ++g) ac[g] += qperm<0xB1>(ac[g]);
        #pragma unroll
        for (int g = 0; g < 4; ++g) ac[g] += qperm<0x4E>(ac[g]);

        const float i_ = sigm_f(ac[0]);
        const float f_ = sigm_f(ac[1]);
        const float g_ = tanh_f(ac[2]);
        const float o_ = sigm_f(ac[3]);
        c = fmaf(f_, c, i_ * g_);
        const float h = o_ * tanh_f(c);

        if (q == 0 && j < H_DIM) {
            hbuf[p ^ 1][hpos] = h;
            hs[(size_t)(t * B_DIM + b) * H_DIM + j] = h;
        }
        asm volatile("s_waitcnt lgkmcnt(0)\ns_barrier" ::: "memory");
        p ^= 1;
        xpv = xp_next;
    }
}

// ---------------------------------------------------------------------------
// Kernel 3: FC. out[t,o] = fc_b[o] + hs[t,:] . fcW[o,:]   (hs row = 5000 dense)
// ---------------------------------------------------------------------------
__global__ __launch_bounds__(256) void fc_kernel(
    const float* __restrict__ hs,    // (T, 5000)
    const float* __restrict__ fcW,   // (2, 5000)
    const float* __restrict__ fcb,
    float* __restrict__ out)         // (T, 2)
{
    const int t   = blockIdx.x;
    const int tid = threadIdx.x;

    float p0 = 0.f, p1 = 0.f;
    for (int k = tid * 4; k < 5000; k += 1024) {
        const float4 hv = *reinterpret_cast<const float4*>(&hs[(size_t)t * 5000 + k]);
        const float4 w0 = *reinterpret_cast<const float4*>(&fcW[k]);
        const float4 w1 = *reinterpret_cast<const float4*>(&fcW[5000 + k]);
        p0 += hv.x * w0.x + hv.y * w0.y + hv.z * w0.z + hv.w * w0.w;
        p1 += hv.x * w1.x + hv.y * w1.y + hv.z * w1.z + hv.w * w1.w;
    }
    #pragma unroll
    for (int off = 32; off > 0; off >>= 1) {
        p0 += __shfl_xor(p0, off);
        p1 += __shfl_xor(p1, off);
    }
    __shared__ float red[8];
    const int wv = tid >> 6;
    if ((tid & 63) == 0) { red[wv * 2] = p0; red[wv * 2 + 1] = p1; }
    __syncthreads();
    if (tid == 0) {
        out[2 * t]     = fcb[0] + red[0] + red[2] + red[4] + red[6];
        out[2 * t + 1] = fcb[1] + red[1] + red[3] + red[5] + red[7];
    }
}

// ---------------------------------------------------------------------------
extern "C" void kernel_launch(void* const* d_in, const int* in_sizes, int n_in,
                              void* d_out, int out_size, void* d_ws, size_t ws_size,
                              hipStream_t stream) {
    const float* x   = (const float*)d_in[0];
    const float* Wih = (const float*)d_in[1];
    const float* Whh = (const float*)d_in[2];
    const float* bih = (const float*)d_in[3];
    const float* bhh = (const float*)d_in[4];
    const float* fcW = (const float*)d_in[5];
    const float* fcb = (const float*)d_in[6];
    float* out = (float*)d_out;

    // ws layout: xp (163.84 MB) | Whi (614.4 KB) | Wlo (614.4 KB) | hs (40.96 MB)
    char* ws = (char*)d_ws;
    float*          xp  = (float*)ws;
    unsigned short* Whi = (unsigned short*)(ws + (size_t)M_DIM * G4 * 4);
    unsigned short* Wlo = Whi + (size_t)G4 * KPAD;
    float*          hs  = (float*)((char*)(Wlo + (size_t)G4 * KPAD));

    wconv<<<(G4 * KPAD + 255) / 256, 256, 0, stream>>>(Wih, Whi, Wlo);

    xproj_mfma<<<M_DIM / 64, 256, 0, stream>>>(x, Whi, Wlo, bih, bhh, xp);

    lstm_scan<<<B_DIM, 448, 0, stream>>>(xp, Whh, hs);

    fc_kernel<<<T_DIM, 256, 0, stream>>>(hs, fcW, fcb, out);
}

// Round 4
// 1493.284 us; speedup vs baseline: 2.2069x; 1.1411x over previous
//
#include <hip/hip_runtime.h>

#define T_DIM 2048
#define B_DIM 50
#define F_DIM 750
#define H_DIM 100
#define G4    400             // 4*H
#define M_DIM (T_DIM * B_DIM) // 102400
#define KPAD  768             // F padded to MFMA-friendly K

typedef __attribute__((ext_vector_type(8))) short short8v;  // 8 bf16
typedef __attribute__((ext_vector_type(4))) float f32x4;

__device__ __forceinline__ float fast_rcp(float x) { return __builtin_amdgcn_rcpf(x); }
__device__ __forceinline__ float sigm_f(float x) {
    return fast_rcp(1.0f + __expf(-x));
}
__device__ __forceinline__ float tanh_f(float x) {
    return 1.0f - 2.0f * fast_rcp(__expf(2.0f * x) + 1.0f);
}

__device__ __forceinline__ unsigned short f2bf_rne(float f) {
    unsigned int u = __float_as_uint(f);
    u = (u + 0x7FFFu + ((u >> 16) & 1u)) >> 16;
    return (unsigned short)u;
}
__device__ __forceinline__ float bf2f(unsigned short h) {
    return __uint_as_float(((unsigned int)h) << 16);
}

template <int CTRL>
__device__ __forceinline__ float qperm(float x) {
    return __int_as_float(__builtin_amdgcn_mov_dpp(__float_as_int(x), CTRL, 0xF, 0xF, false));
}

// ---------------------------------------------------------------------------
// Kernel 0: W_ih (400x750 fp32) -> W_hi/W_lo (400x768 bf16, k-padded 0). RNE.
// ---------------------------------------------------------------------------
__global__ __launch_bounds__(256) void wconv(
    const float* __restrict__ W,
    unsigned short* __restrict__ Whi,
    unsigned short* __restrict__ Wlo)
{
    int i = blockIdx.x * 256 + threadIdx.x;
    if (i >= G4 * KPAD) return;
    int g = i / KPAD, k = i - g * KPAD;
    float v = (k < F_DIM) ? W[g * F_DIM + k] : 0.f;
    unsigned short h = f2bf_rne(v);
    Whi[i] = h;
    Wlo[i] = f2bf_rne(v - bf2f(h));
}

// ---------------------------------------------------------------------------
// Kernel 1: xp = x @ W_ih^T + b via bf16 split MFMA.
//   T14 async-stage: issue next k-step's global loads BEFORE the MFMA cluster,
//   convert (truncation split, 4 VALU/elem) + ds_write AFTER it.
// ---------------------------------------------------------------------------
__global__ __launch_bounds__(256, 2) void xproj_mfma(
    const float* __restrict__ x,            // (M, 750)
    const unsigned short* __restrict__ Whi, // (400, 768) bf16
    const unsigned short* __restrict__ Wlo,
    const float* __restrict__ bih,
    const float* __restrict__ bhh,
    float* __restrict__ xp)                 // (M, 400)
{
    const int m0   = blockIdx.x * 64;
    const int tid  = threadIdx.x;
    const int lane = tid & 63;
    const int w    = tid >> 6;            // wave 0..3
    const int fr   = lane & 15;           // frag row/col within 16
    const int fk   = (lane >> 4) * 8;     // frag k-offset (8 contiguous)

    __shared__ unsigned short Ahi[2][64][40];
    __shared__ unsigned short Alo[2][64][40];

    f32x4 acc[4][7];
    #pragma unroll
    for (int s = 0; s < 4; ++s)
        #pragma unroll
        for (int t = 0; t < 7; ++t)
            acc[s][t] = (f32x4){0.f, 0.f, 0.f, 0.f};

    float bias_t[7];
    #pragma unroll
    for (int tt = 0; tt < 7; ++tt) {
        const int nt = w + 4 * tt;
        if (nt < 25) {
            const int n = nt * 16 + fr;
            bias_t[tt] = bih[n] + bhh[n];
        } else bias_t[tt] = 0.f;
    }

    const int sr = tid >> 2;          // row 0..63
    const int sc = (tid & 3) * 8;     // k-chunk 0/8/16/24
    const float* xrow = x + (size_t)(m0 + sr) * F_DIM;

    float f[8];

    #define STAGE_LOAD(KS)                                                     \
    {                                                                          \
        const int kg = (KS) * 32 + sc;                                         \
        _Pragma("unroll")                                                      \
        for (int i = 0; i < 8; i += 2) {                                       \
            if (kg + i + 1 < F_DIM) {                                          \
                float2 v = *reinterpret_cast<const float2*>(&xrow[kg + i]);    \
                f[i] = v.x; f[i + 1] = v.y;                                    \
            } else {                                                           \
                f[i]     = (kg + i < F_DIM) ? xrow[kg + i] : 0.f;              \
                f[i + 1] = 0.f;                                                \
            }                                                                  \
        }                                                                      \
    }

    // truncation split: hi = RTZ-bf16(f), lo = RTZ-bf16(f - hi). 4 VALU/elem.
    #define STAGE_WRITE(NB)                                                    \
    {                                                                          \
        short8v vh, vl;                                                        \
        _Pragma("unroll")                                                      \
        for (int i = 0; i < 8; ++i) {                                          \
            unsigned int u = __float_as_uint(f[i]);                            \
            vh[i] = (short)(u >> 16);                                          \
            float r = f[i] - __uint_as_float(u & 0xffff0000u);                 \
            vl[i] = (short)(__float_as_uint(r) >> 16);                         \
        }                                                                      \
        *reinterpret_cast<short8v*>(&Ahi[NB][sr][sc]) = vh;                    \
        *reinterpret_cast<short8v*>(&Alo[NB][sr][sc]) = vl;                    \
    }

    STAGE_LOAD(0);
    STAGE_WRITE(0);
    asm volatile("s_waitcnt lgkmcnt(0)\ns_barrier" ::: "memory");

    for (int s = 0; s < 24; ++s) {
        const int cur = s & 1;
        short8v ah[4], al[4];
        #pragma unroll
        for (int st = 0; st < 4; ++st) {
            ah[st] = *reinterpret_cast<const short8v*>(&Ahi[cur][st * 16 + fr][fk]);
            al[st] = *reinterpret_cast<const short8v*>(&Alo[cur][st * 16 + fr][fk]);
        }

        if (s < 23) STAGE_LOAD(s + 1);    // issue loads early; consume after MFMA

        const int kb = s * 32 + fk;
        #pragma unroll
        for (int tt = 0; tt < 7; ++tt) {
            const int nt = w + 4 * tt;
            if (nt < 25) {
                const int n = nt * 16 + fr;
                const short8v bh = *reinterpret_cast<const short8v*>(&Whi[n * KPAD + kb]);
                const short8v bl = *reinterpret_cast<const short8v*>(&Wlo[n * KPAD + kb]);
                #pragma unroll
                for (int st = 0; st < 4; ++st) {
                    acc[st][tt] = __builtin_amdgcn_mfma_f32_16x16x32_bf16(ah[st], bh, acc[st][tt], 0, 0, 0);
                    acc[st][tt] = __builtin_amdgcn_mfma_f32_16x16x32_bf16(ah[st], bl, acc[st][tt], 0, 0, 0);
                    acc[st][tt] = __builtin_amdgcn_mfma_f32_16x16x32_bf16(al[st], bh, acc[st][tt], 0, 0, 0);
                }
            }
        }

        if (s < 23) STAGE_WRITE(cur ^ 1); // vmcnt wait happens here, after MFMAs
        asm volatile("s_waitcnt lgkmcnt(0)\ns_barrier" ::: "memory");
    }

    // C/D layout: col = lane&15, row = (lane>>4)*4 + reg  [m89-verified]
    #pragma unroll
    for (int tt = 0; tt < 7; ++tt) {
        const int nt = w + 4 * tt;
        if (nt < 25) {
            const int n = nt * 16 + fr;
            #pragma unroll
            for (int st = 0; st < 4; ++st) {
                #pragma unroll
                for (int r = 0; r < 4; ++r) {
                    const int m = m0 + st * 16 + (lane >> 4) * 4 + r;
                    xp[(size_t)m * G4 + n] = acc[st][tt][r] + bias_t[tt];
                }
            }
        }
    }
    #undef STAGE_LOAD
    #undef STAGE_WRITE
}

// ---------------------------------------------------------------------------
// Kernel 2: LSTM scan, quarter-split quad cell, weights pinned in VGPRs.
//   launch_bounds(448,1): min 1 wave/EU -> VGPR cap high enough for w[4][28].
//   Lane-specialized activation + DPP quad broadcast of i,f,g,o.
// ---------------------------------------------------------------------------
__global__ __launch_bounds__(448, 1) void lstm_scan(
    const float* __restrict__ xp,    // (T*B, 400)
    const float* __restrict__ Whh,   // (400, 100)
    float* __restrict__ hs)          // (T*B, 100)
{
    const int b   = blockIdx.x;
    const int tid = threadIdx.x;
    const int q   = tid & 3;         // k-quarter / gate for activation
    const int j   = tid >> 2;        // hidden unit 0..111
    const int jc  = (j < H_DIM) ? j : (H_DIM - 1);
    const int row = q * H_DIM + jc;  // xp column for gate q of unit j

    __shared__ __align__(16) float hbuf[2][112];

    float w[4][28];
    #pragma unroll
    for (int g = 0; g < 4; ++g) {
        const size_t base = (size_t)(g * H_DIM + jc) * H_DIM + 25 * q;
        #pragma unroll
        for (int r = 0; r < 25; ++r) w[g][r] = Whh[base + r];
        w[g][25] = w[g][26] = w[g][27] = 0.f;
    }
    if (tid < 112) { hbuf[0][tid] = 0.f; hbuf[1][tid] = 0.f; }

    const int hpos = (jc / 25) * 28 + (jc % 25);
    const bool writer = (q == 0) && (j < H_DIM);

    // unified activation constants: act = s*sigm(s*x) - (s-1); s=2 for tanh gate
    const float s_act = (q == 2) ? 2.0f : 1.0f;
    const float nsl2  = -s_act * 1.44269504088896f;  // exp2 scale
    const float nsm1  = 1.0f - s_act;

    float c = 0.f;
    const float* xp_ptr = xp + (size_t)b * G4 + row;
    float*       hs_ptr = hs + (size_t)b * H_DIM + j;
    float xpv = *xp_ptr;
    __syncthreads();

    int p = 0;
    for (int t = 0; t < T_DIM; ++t) {
        float xp_next = 0.f;
        if (t != T_DIM - 1) {                     // uniform branch (SALU)
            xp_ptr += B_DIM * G4;
            xp_next = *xp_ptr;
        }

        float ac0 = (q == 0) ? xpv : 0.f;
        float ac1 = (q == 1) ? xpv : 0.f;
        float ac2 = (q == 2) ? xpv : 0.f;
        float ac3 = (q == 3) ? xpv : 0.f;
        #pragma unroll
        for (int k4 = 0; k4 < 7; ++k4) {
            float4 hv = *reinterpret_cast<const float4*>(&hbuf[p][28 * q + 4 * k4]);
            ac0 = fmaf(w[0][4 * k4 + 0], hv.x, ac0);
            ac0 = fmaf(w[0][4 * k4 + 1], hv.y, ac0);
            ac0 = fmaf(w[0][4 * k4 + 2], hv.z, ac0);
            ac0 = fmaf(w[0][4 * k4 + 3], hv.w, ac0);
            ac1 = fmaf(w[1][4 * k4 + 0], hv.x, ac1);
            ac1 = fmaf(w[1][4 * k4 + 1], hv.y, ac1);
            ac1 = fmaf(w[1][4 * k4 + 2], hv.z, ac1);
            ac1 = fmaf(w[1][4 * k4 + 3], hv.w, ac1);
            ac2 = fmaf(w[2][4 * k4 + 0], hv.x, ac2);
            ac2 = fmaf(w[2][4 * k4 + 1], hv.y, ac2);
            ac2 = fmaf(w[2][4 * k4 + 2], hv.z, ac2);
            ac2 = fmaf(w[2][4 * k4 + 3], hv.w, ac2);
            ac3 = fmaf(w[3][4 * k4 + 0], hv.x, ac3);
            ac3 = fmaf(w[3][4 * k4 + 1], hv.y, ac3);
            ac3 = fmaf(w[3][4 * k4 + 2], hv.z, ac3);
            ac3 = fmaf(w[3][4 * k4 + 3], hv.w, ac3);
        }
        // quad butterfly: full dot sums (incl. each gate's xp term) in all lanes
        ac0 += qperm<0xB1>(ac0);
        ac1 += qperm<0xB1>(ac1);
        ac2 += qperm<0xB1>(ac2);
        ac3 += qperm<0xB1>(ac3);
        ac0 += qperm<0x4E>(ac0);
        ac1 += qperm<0x4E>(ac1);
        ac2 += qperm<0x4E>(ac2);
        ac3 += qperm<0x4E>(ac3);

        // this lane activates only gate q
        float pre = ac0;
        pre = (q == 1) ? ac1 : pre;
        pre = (q == 2) ? ac2 : pre;
        pre = (q == 3) ? ac3 : pre;
        float act = fmaf(s_act, fast_rcp(1.0f + __builtin_amdgcn_exp2f(nsl2 * pre)), nsm1);

        // broadcast i,f,g,o across the quad
        float i_ = qperm<0x00>(act);
        float f_ = qperm<0x55>(act);
        float g_ = qperm<0xAA>(act);
        float o_ = qperm<0xFF>(act);

        c = fmaf(f_, c, i_ * g_);
        const float h = o_ * tanh_f(c);

        if (writer) {
            hbuf[p ^ 1][hpos] = h;
            *hs_ptr = h;
        }
        hs_ptr += B_DIM * H_DIM;
        asm volatile("s_waitcnt lgkmcnt(0)\ns_barrier" ::: "memory");
        p ^= 1;
        xpv = xp_next;
    }
}

// ---------------------------------------------------------------------------
// Kernel 3: FC. out[t,o] = fc_b[o] + hs[t,:] . fcW[o,:]
// ---------------------------------------------------------------------------
__global__ __launch_bounds__(256) void fc_kernel(
    const float* __restrict__ hs,    // (T, 5000)
    const float* __restrict__ fcW,   // (2, 5000)
    const float* __restrict__ fcb,
    float* __restrict__ out)         // (T, 2)
{
    const int t   = blockIdx.x;
    const int tid = threadIdx.x;

    float p0 = 0.f, p1 = 0.f;
    for (int k = tid * 4; k < 5000; k += 1024) {
        const float4 hv = *reinterpret_cast<const float4*>(&hs[(size_t)t * 5000 + k]);
        const float4 w0 = *reinterpret_cast<const float4*>(&fcW[k]);
        const float4 w1 = *reinterpret_cast<const float4*>(&fcW[5000 + k]);
        p0 += hv.x * w0.x + hv.y * w0.y + hv.z * w0.z + hv.w * w0.w;
        p1 += hv.x * w1.x + hv.y * w1.y + hv.z * w1.z + hv.w * w1.w;
    }
    #pragma unroll
    for (int off = 32; off > 0; off >>= 1) {
        p0 += __shfl_xor(p0, off);
        p1 += __shfl_xor(p1, off);
    }
    __shared__ float red[8];
    const int wv = tid >> 6;
    if ((tid & 63) == 0) { red[wv * 2] = p0; red[wv * 2 + 1] = p1; }
    __syncthreads();
    if (tid == 0) {
        out[2 * t]     = fcb[0] + red[0] + red[2] + red[4] + red[6];
        out[2 * t + 1] = fcb[1] + red[1] + red[3] + red[5] + red[7];
    }
}

// ---------------------------------------------------------------------------
extern "C" void kernel_launch(void* const* d_in, const int* in_sizes, int n_in,
                              void* d_out, int out_size, void* d_ws, size_t ws_size,
                              hipStream_t stream) {
    const float* x   = (const float*)d_in[0];
    const float* Wih = (const float*)d_in[1];
    const float* Whh = (const float*)d_in[2];
    const float* bih = (const float*)d_in[3];
    const float* bhh = (const float*)d_in[4];
    const float* fcW = (const float*)d_in[5];
    const float* fcb = (const float*)d_in[6];
    float* out = (float*)d_out;

    // ws layout: xp (163.84 MB) | Whi (614.4 KB) | Wlo (614.4 KB) | hs (40.96 MB)
    char* ws = (char*)d_ws;
    float*          xp  = (float*)ws;
    unsigned short* Whi = (unsigned short*)(ws + (size_t)M_DIM * G4 * 4);
    unsigned short* Wlo = Whi + (size_t)G4 * KPAD;
    float*          hs  = (float*)((char*)(Wlo + (size_t)G4 * KPAD));

    wconv<<<(G4 * KPAD + 255) / 256, 256, 0, stream>>>(Wih, Whi, Wlo);

    xproj_mfma<<<M_DIM / 64, 256, 0, stream>>>(x, Whi, Wlo, bih, bhh, xp);

    lstm_scan<<<B_DIM, 448, 0, stream>>>(xp, Whh, hs);

    fc_kernel<<<T_DIM, 256, 0, stream>>>(hs, fcW, fcb, out);
}